// Round 2
// baseline (808.816 us; speedup 1.0000x reference)
//
#include <hip/hip_runtime.h>
#include <hip/hip_bf16.h>

// Problem constants (from reference)
#define NN 50000
#define EE 800000
#define IN_F 128
#define HID 64
#define OUT_F 64
#define KK 3
// fc widths: K*HID = K*OUT_F = 192
#define FCW 192

// C[N,192] = A[N,Kdim] @ B[Kdim,192].  4 rows per 256-thread block,
// 64 lanes per row, each lane computes cols {l, l+64, l+128}.
__global__ void gemm_rowtile(const float* __restrict__ A,
                             const float* __restrict__ B,
                             float* __restrict__ C,
                             int N, int Kdim) {
    int row  = blockIdx.x * 4 + (threadIdx.x >> 6);
    int lane = threadIdx.x & 63;
    if (row >= N) return;
    const float* a = A + (long)row * Kdim;
    float acc0 = 0.f, acc1 = 0.f, acc2 = 0.f;
    for (int c = 0; c < Kdim; ++c) {
        float av = a[c];
        const float* b = B + c * FCW + lane;
        acc0 = fmaf(av, b[0],   acc0);
        acc1 = fmaf(av, b[64],  acc1);
        acc2 = fmaf(av, b[128], acc2);
    }
    float* cp = C + (long)row * FCW + lane;
    cp[0]   = acc0;
    cp[64]  = acc1;
    cp[128] = acc2;
}

// out[n, f] = bias[f]   (pre-initialize aggregation target with bias)
__global__ void init_bias(float* __restrict__ out,
                          const float* __restrict__ bias, int total) {
    int i = blockIdx.x * 256 + threadIdx.x;
    if (i < total) out[i] = bias[i & 63];
}

// Edge phase: one 64-lane group per edge; lane = output feature.
// msg[f] = sum_k w[e,k] * hp[src[e], k*64 + f];  atomicAdd into out[dst[e], f].
__global__ void edge_aggregate(const float* __restrict__ hp,      // [N,192]
                               const float* __restrict__ pseudo,  // [E,2]
                               const int* __restrict__ src,
                               const int* __restrict__ dst,
                               const float* __restrict__ pw,      // [2,2]
                               const float* __restrict__ pb,      // [2]
                               const float* __restrict__ mu,      // [3,2]
                               const float* __restrict__ isig,    // [3,2]
                               float* __restrict__ out,           // [N,64] (bias-initialized)
                               int E) {
    int e    = blockIdx.x * 4 + (threadIdx.x >> 6);
    int lane = threadIdx.x & 63;
    if (e >= E) return;

    float2 p = ((const float2*)pseudo)[e];
    // u = tanh(p @ pw + pb); pw row-major [2][2]
    float u0 = tanhf(fmaf(p.x, pw[0], fmaf(p.y, pw[2], pb[0])));
    float u1 = tanhf(fmaf(p.x, pw[1], fmaf(p.y, pw[3], pb[1])));

    int s = src[e];
    int d = dst[e];
    const float* h = hp + (long)s * FCW + lane;

    float msg = 0.f;
#pragma unroll
    for (int k = 0; k < KK; ++k) {
        float d0 = (u0 - mu[k * 2 + 0]) * isig[k * 2 + 0];
        float d1 = (u1 - mu[k * 2 + 1]) * isig[k * 2 + 1];
        float w  = __expf(-0.5f * (d0 * d0 + d1 * d1));
        msg = fmaf(w, h[k * 64], msg);
    }
    atomicAdd(out + (long)d * 64 + lane, msg);
}

extern "C" void kernel_launch(void* const* d_in, const int* in_sizes, int n_in,
                              void* d_out, int out_size, void* d_ws, size_t ws_size,
                              hipStream_t stream) {
    const float* feat   = (const float*)d_in[0];
    const float* pseudo = (const float*)d_in[1];
    const int*   src    = (const int*)d_in[2];
    const int*   dst    = (const int*)d_in[3];
    const float* fc0    = (const float*)d_in[4];
    const float* mu0    = (const float*)d_in[5];
    const float* isig0  = (const float*)d_in[6];
    const float* bias0  = (const float*)d_in[7];
    const float* pw0    = (const float*)d_in[8];
    const float* pb0    = (const float*)d_in[9];
    const float* fc1    = (const float*)d_in[10];
    const float* mu1    = (const float*)d_in[11];
    const float* isig1  = (const float*)d_in[12];
    const float* bias1  = (const float*)d_in[13];
    const float* pw1    = (const float*)d_in[14];
    const float* pb1    = (const float*)d_in[15];

    float* hp   = (float*)d_ws;                       // [N,192]  38.4 MB (reused both layers)
    float* agg0 = hp + (long)NN * FCW;                // [N,64]   12.8 MB
    float* out  = (float*)d_out;                      // [N,64]

    dim3 blk(256);
    dim3 grid_rows((NN + 3) / 4);       // 4 rows/block
    dim3 grid_edges((EE + 3) / 4);      // 4 edges/block
    dim3 grid_init((NN * 64 + 255) / 256);

    // ---- layer 0 ----
    init_bias<<<grid_init, blk, 0, stream>>>(agg0, bias0, NN * 64);
    gemm_rowtile<<<grid_rows, blk, 0, stream>>>(feat, fc0, hp, NN, IN_F);
    edge_aggregate<<<grid_edges, blk, 0, stream>>>(hp, pseudo, src, dst,
                                                   pw0, pb0, mu0, isig0,
                                                   agg0, EE);
    // ---- layer 1 ----  (h = agg0 already includes bias0)
    gemm_rowtile<<<grid_rows, blk, 0, stream>>>(agg0, fc1, hp, NN, HID);
    init_bias<<<grid_init, blk, 0, stream>>>(out, bias1, NN * 64);
    edge_aggregate<<<grid_edges, blk, 0, stream>>>(hp, pseudo, src, dst,
                                                   pw1, pb1, mu1, isig1,
                                                   out, EE);
}

// Round 7
// 589.116 us; speedup vs baseline: 1.3729x; 1.3729x over previous
//
#include <hip/hip_runtime.h>
#include <hip/hip_bf16.h>

// Problem constants (from reference)
#define NN 50000
#define EE 800000
#define IN_F 128
#define HID 64
#define OUT_F 64
#define KK 3
#define FCW 192   // K*HID == K*OUT_F == 192

// C[N,192] = A[N,Kdim] @ B[Kdim,192].
// Block = 256 threads -> 32-row x 192-col tile.
// A-tile (32 x Kdim floats, contiguous) staged in LDS via float4.
// Wave w owns rows w*8..w*8+7; lane owns cols {l, l+64, l+128}.
// acc[8][3] = 24 independent chains -> ILP (fixes round-2's VGPR=8 latency bind).
__global__ __launch_bounds__(256) void gemm_tile(const float* __restrict__ A,
                                                 const float* __restrict__ B,
                                                 float* __restrict__ C,
                                                 int N, int Kdim) {
    __shared__ float sA[32 * 128];   // max Kdim = 128 -> 16 KB
    const int row0 = blockIdx.x * 32;
    const int tid  = threadIdx.x;
    const int lane = tid & 63;
    const int wave = tid >> 6;

    int tile_rows = N - row0;
    if (tile_rows > 32) tile_rows = 32;

    // Stage A tile: rows are contiguous (full-K staging) -> one linear copy.
    {
        const int n4 = tile_rows * Kdim / 4;
        const float4* __restrict__ src = (const float4*)(A + (long)row0 * Kdim);
        float4* dst = (float4*)sA;
        for (int i = tid; i < n4; i += 256) dst[i] = src[i];
    }
    __syncthreads();

    float acc[8][3];
#pragma unroll
    for (int r = 0; r < 8; ++r) acc[r][0] = acc[r][1] = acc[r][2] = 0.f;

    const float* __restrict__ sa = sA + wave * 8 * Kdim;
    const float* __restrict__ bp = B + lane;
#pragma unroll 2
    for (int k = 0; k < Kdim; ++k) {
        const float b0 = bp[k * FCW];
        const float b1 = bp[k * FCW + 64];
        const float b2 = bp[k * FCW + 128];
#pragma unroll
        for (int r = 0; r < 8; ++r) {
            const float av = sa[r * Kdim + k];   // wave-uniform LDS broadcast
            acc[r][0] = fmaf(av, b0, acc[r][0]);
            acc[r][1] = fmaf(av, b1, acc[r][1]);
            acc[r][2] = fmaf(av, b2, acc[r][2]);
        }
    }

    const int rbase = row0 + wave * 8;
#pragma unroll
    for (int r = 0; r < 8; ++r) {
        const int row = rbase + r;
        if (row < N) {
            float* cp = C + (long)row * FCW + lane;
            cp[0]   = acc[r][0];
            cp[64]  = acc[r][1];
            cp[128] = acc[r][2];
        }
    }
}

// out[n, f] = bias[f]   (pre-initialize aggregation target with bias)
__global__ void init_bias(float* __restrict__ out,
                          const float* __restrict__ bias, int total) {
    int i = blockIdx.x * 256 + threadIdx.x;
    if (i < total) out[i] = bias[i & 63];
}

// Edge phase: one 64-lane group per edge; lane = output feature.
__global__ void edge_aggregate(const float* __restrict__ hp,      // [N,192]
                               const float* __restrict__ pseudo,  // [E,2]
                               const int* __restrict__ src,
                               const int* __restrict__ dst,
                               const float* __restrict__ pw,      // [2,2]
                               const float* __restrict__ pb,      // [2]
                               const float* __restrict__ mu,      // [3,2]
                               const float* __restrict__ isig,    // [3,2]
                               float* __restrict__ out,           // [N,64] (bias-initialized)
                               int E) {
    int e    = blockIdx.x * 4 + (threadIdx.x >> 6);
    int lane = threadIdx.x & 63;
    if (e >= E) return;

    float2 p = ((const float2*)pseudo)[e];
    float u0 = tanhf(fmaf(p.x, pw[0], fmaf(p.y, pw[2], pb[0])));
    float u1 = tanhf(fmaf(p.x, pw[1], fmaf(p.y, pw[3], pb[1])));

    int s = src[e];
    int d = dst[e];
    const float* h = hp + (long)s * FCW + lane;

    float msg = 0.f;
#pragma unroll
    for (int k = 0; k < KK; ++k) {
        float d0 = (u0 - mu[k * 2 + 0]) * isig[k * 2 + 0];
        float d1 = (u1 - mu[k * 2 + 1]) * isig[k * 2 + 1];
        float w  = __expf(-0.5f * (d0 * d0 + d1 * d1));
        msg = fmaf(w, h[k * 64], msg);
    }
    atomicAdd(out + (long)d * 64 + lane, msg);
}

extern "C" void kernel_launch(void* const* d_in, const int* in_sizes, int n_in,
                              void* d_out, int out_size, void* d_ws, size_t ws_size,
                              hipStream_t stream) {
    const float* feat   = (const float*)d_in[0];
    const float* pseudo = (const float*)d_in[1];
    const int*   src    = (const int*)d_in[2];
    const int*   dst    = (const int*)d_in[3];
    const float* fc0    = (const float*)d_in[4];
    const float* mu0    = (const float*)d_in[5];
    const float* isig0  = (const float*)d_in[6];
    const float* bias0  = (const float*)d_in[7];
    const float* pw0    = (const float*)d_in[8];
    const float* pb0    = (const float*)d_in[9];
    const float* fc1    = (const float*)d_in[10];
    const float* mu1    = (const float*)d_in[11];
    const float* isig1  = (const float*)d_in[12];
    const float* bias1  = (const float*)d_in[13];
    const float* pw1    = (const float*)d_in[14];
    const float* pb1    = (const float*)d_in[15];

    float* hp   = (float*)d_ws;                       // [N,192]  38.4 MB
    float* agg0 = hp + (long)NN * FCW;                // [N,64]   12.8 MB
    float* out  = (float*)d_out;                      // [N,64]

    dim3 blk(256);
    dim3 grid_gemm((NN + 31) / 32);
    dim3 grid_edges((EE + 3) / 4);
    dim3 grid_init((NN * 64 + 255) / 256);

    // ---- layer 0 ----
    init_bias<<<grid_init, blk, 0, stream>>>(agg0, bias0, NN * 64);
    gemm_tile<<<grid_gemm, blk, 0, stream>>>(feat, fc0, hp, NN, IN_F);
    edge_aggregate<<<grid_edges, blk, 0, stream>>>(hp, pseudo, src, dst,
                                                   pw0, pb0, mu0, isig0,
                                                   agg0, EE);
    // ---- layer 1 ----  (agg0 already includes bias0)
    gemm_tile<<<grid_gemm, blk, 0, stream>>>(agg0, fc1, hp, NN, HID);
    init_bias<<<grid_init, blk, 0, stream>>>(out, bias1, NN * 64);
    edge_aggregate<<<grid_edges, blk, 0, stream>>>(hp, pseudo, src, dst,
                                                   pw1, pb1, mu1, isig1,
                                                   out, EE);
}

// Round 8
// 556.723 us; speedup vs baseline: 1.4528x; 1.0582x over previous
//
#include <hip/hip_runtime.h>
#include <hip/hip_bf16.h>

// Problem constants (from reference)
#define NN 50000
#define EE 800000
#define IN_F 128
#define HID 64
#define OUT_F 64
#define KK 3
#define FCW 192   // K*HID == K*OUT_F == 192

// C[N,192] = A[N,Kdim] @ B[Kdim,192].
// Block = 256 threads -> 32-row x 192-col tile; A-tile in LDS; acc[8][3] ILP.
__global__ __launch_bounds__(256) void gemm_tile(const float* __restrict__ A,
                                                 const float* __restrict__ B,
                                                 float* __restrict__ C,
                                                 int N, int Kdim) {
    __shared__ float sA[32 * 128];
    const int row0 = blockIdx.x * 32;
    const int tid  = threadIdx.x;
    const int lane = tid & 63;
    const int wave = tid >> 6;

    int tile_rows = N - row0;
    if (tile_rows > 32) tile_rows = 32;

    {
        const int n4 = tile_rows * Kdim / 4;
        const float4* __restrict__ src = (const float4*)(A + (long)row0 * Kdim);
        float4* dst = (float4*)sA;
        for (int i = tid; i < n4; i += 256) dst[i] = src[i];
    }
    __syncthreads();

    float acc[8][3];
#pragma unroll
    for (int r = 0; r < 8; ++r) acc[r][0] = acc[r][1] = acc[r][2] = 0.f;

    const float* __restrict__ sa = sA + wave * 8 * Kdim;
    const float* __restrict__ bp = B + lane;
#pragma unroll 2
    for (int k = 0; k < Kdim; ++k) {
        const float b0 = bp[k * FCW];
        const float b1 = bp[k * FCW + 64];
        const float b2 = bp[k * FCW + 128];
#pragma unroll
        for (int r = 0; r < 8; ++r) {
            const float av = sa[r * Kdim + k];
            acc[r][0] = fmaf(av, b0, acc[r][0]);
            acc[r][1] = fmaf(av, b1, acc[r][1]);
            acc[r][2] = fmaf(av, b2, acc[r][2]);
        }
    }

    const int rbase = row0 + wave * 8;
#pragma unroll
    for (int r = 0; r < 8; ++r) {
        const int row = rbase + r;
        if (row < N) {
            float* cp = C + (long)row * FCW + lane;
            cp[0]   = acc[r][0];
            cp[64]  = acc[r][1];
            cp[128] = acc[r][2];
        }
    }
}

// out[n, f] = bias[f]
__global__ void init_bias(float* __restrict__ out,
                          const float* __restrict__ bias, int total) {
    int i = blockIdx.x * 256 + threadIdx.x;
    if (i < total) out[i] = bias[i & 63];
}

// One thread per edge: compute the 3 Gaussian kernel weights once.
// (In the aggregate kernel these were whole-wave transcendentals -> 60% VALUBusy.)
__global__ void edge_weights(const float2* __restrict__ pseudo,
                             const float* __restrict__ pw,   // [2,2]
                             const float* __restrict__ pb,   // [2]
                             const float* __restrict__ mu,   // [3,2]
                             const float* __restrict__ isig, // [3,2]
                             float4* __restrict__ w4, int E) {
    int e = blockIdx.x * 256 + threadIdx.x;
    if (e >= E) return;
    float2 p = pseudo[e];
    float u0 = tanhf(fmaf(p.x, pw[0], fmaf(p.y, pw[2], pb[0])));
    float u1 = tanhf(fmaf(p.x, pw[1], fmaf(p.y, pw[3], pb[1])));
    float w[KK];
#pragma unroll
    for (int k = 0; k < KK; ++k) {
        float d0 = (u0 - mu[k * 2 + 0]) * isig[k * 2 + 0];
        float d1 = (u1 - mu[k * 2 + 1]) * isig[k * 2 + 1];
        w[k] = __expf(-0.5f * (d0 * d0 + d1 * d1));
    }
    w4[e] = make_float4(w[0], w[1], w[2], 0.f);
}

// Slim edge aggregation: 2 edges per wave (MLP), broadcast w4/src/dst,
// 3 gather loads + 3 FMA + 1 atomic per edge per lane.
__global__ __launch_bounds__(256) void edge_aggregate2(const float* __restrict__ hp,  // [N,192]
                                                       const float4* __restrict__ w4, // [E]
                                                       const int* __restrict__ src,
                                                       const int* __restrict__ dst,
                                                       float* __restrict__ out,       // [N,64]
                                                       int E) {
    const int wave = threadIdx.x >> 6;
    const int lane = threadIdx.x & 63;
    const int e0 = (blockIdx.x * 4 + wave) * 2;
    const int e1 = e0 + 1;
    if (e0 >= E) return;

    // edge 0 loads
    const float4 wa = w4[e0];
    const int sa = src[e0];
    const int da = dst[e0];
    const float* ha = hp + (long)sa * FCW + lane;
    const float a0 = ha[0], a1 = ha[64], a2 = ha[128];

    // edge 1 loads (issued before edge-0 FMAs for overlap)
    const bool has1 = (e1 < E);
    float b0 = 0.f, b1 = 0.f, b2 = 0.f;
    float4 wb = make_float4(0.f, 0.f, 0.f, 0.f);
    int db = 0;
    if (has1) {
        wb = w4[e1];
        const int sb = src[e1];
        db = dst[e1];
        const float* hb = hp + (long)sb * FCW + lane;
        b0 = hb[0]; b1 = hb[64]; b2 = hb[128];
    }

    const float msga = fmaf(wa.x, a0, fmaf(wa.y, a1, wa.z * a2));
    atomicAdd(out + (long)da * 64 + lane, msga);
    if (has1) {
        const float msgb = fmaf(wb.x, b0, fmaf(wb.y, b1, wb.z * b2));
        atomicAdd(out + (long)db * 64 + lane, msgb);
    }
}

extern "C" void kernel_launch(void* const* d_in, const int* in_sizes, int n_in,
                              void* d_out, int out_size, void* d_ws, size_t ws_size,
                              hipStream_t stream) {
    const float*  feat   = (const float*)d_in[0];
    const float2* pseudo = (const float2*)d_in[1];
    const int*    src    = (const int*)d_in[2];
    const int*    dst    = (const int*)d_in[3];
    const float*  fc0    = (const float*)d_in[4];
    const float*  mu0    = (const float*)d_in[5];
    const float*  isig0  = (const float*)d_in[6];
    const float*  bias0  = (const float*)d_in[7];
    const float*  pw0    = (const float*)d_in[8];
    const float*  pb0    = (const float*)d_in[9];
    const float*  fc1    = (const float*)d_in[10];
    const float*  mu1    = (const float*)d_in[11];
    const float*  isig1  = (const float*)d_in[12];
    const float*  bias1  = (const float*)d_in[13];
    const float*  pw1    = (const float*)d_in[14];
    const float*  pb1    = (const float*)d_in[15];

    float* hp   = (float*)d_ws;                 // [N,192]  38.4 MB
    float* agg0 = hp + (long)NN * FCW;          // [N,64]   12.8 MB
    float* out  = (float*)d_out;                // [N,64]   12.8 MB

    // w4 scratch without growing ws (51.2 MB total, validated round 2):
    //  - layer 0: d_out is dead until layer-1 init -> use it (E*16B == out bytes).
    //  - layer 1: agg0 is dead after gemm1 reads it -> reuse its region.
    float4* w4_l0 = (float4*)d_out;
    float4* w4_l1 = (float4*)agg0;

    dim3 blk(256);
    dim3 grid_gemm((NN + 31) / 32);
    dim3 grid_edges((EE + 7) / 8);          // 8 edges/block (2 per wave)
    dim3 grid_ew((EE + 255) / 256);
    dim3 grid_init((NN * 64 + 255) / 256);

    // ---- layer 0 ----
    init_bias<<<grid_init, blk, 0, stream>>>(agg0, bias0, NN * 64);
    gemm_tile<<<grid_gemm, blk, 0, stream>>>(feat, fc0, hp, NN, IN_F);
    edge_weights<<<grid_ew, blk, 0, stream>>>(pseudo, pw0, pb0, mu0, isig0, w4_l0, EE);
    edge_aggregate2<<<grid_edges, blk, 0, stream>>>(hp, w4_l0, src, dst, agg0, EE);

    // ---- layer 1 ----  (agg0 already includes bias0)
    gemm_tile<<<grid_gemm, blk, 0, stream>>>(agg0, fc1, hp, NN, HID);
    edge_weights<<<grid_ew, blk, 0, stream>>>(pseudo, pw1, pb1, mu1, isig1, w4_l1, EE);
    init_bias<<<grid_init, blk, 0, stream>>>(out, bias1, NN * 64);
    edge_aggregate2<<<grid_edges, blk, 0, stream>>>(hp, w4_l1, src, dst, out, EE);
}